// Round 10
// baseline (356.290 us; speedup 1.0000x reference)
//
#include <hip/hip_runtime.h>
#include <cstdint>
#include <cstddef>

// Binarized basic block on MI355X.
// |acc| <= 9*128 = 1152 < THRESH=8000 -> the per-partial-sum clip never binds
// -> both convs are exact int convolutions of sign() values. int8 implicit
// GEMM via mfma_i32_16x16x64_i8; float ops bit-exact vs numpy fp32.
//
// R19 (on R18's counted-wait asm loop): O-SPLIT -> 2 BLOCKS/CU, 4 WAVES/SIMD.
//  R18 closed the wait/schedule axis (all counts hand-placed, null). Pipe
//  accounting: serialized floors ~1.7k cyc/step vs measured 4.5k with no
//  pipe >20% busy -> per-wave serial chain ~2.2k cyc and the 2 waves/SIMD
//  don't overlap (R13's 1-wave/SIMD regression + R12==R18 both fit).
//  -> Halve the per-wave chain and double the waves/SIMD: each block owns
//     64 O (o = ohalf*64 + l15*4 + n; split on the l15 MULTIPLIER so phase-1
//     stores stay 64-B-aligned sectors -- R10's partial-line bug designed
//     out). LDS 73,728 B -> 2 blocks/CU. Per-CU MFMA/LDS bytes unchanged;
//     per-wave step = 4 ds_read + RG glb + 8 MFMA. Counted waits: vmcnt(2RG),
//     lgkmcnt(4). __launch_bounds__(512,4) caps VGPR at 128 (est ~112).
//  Tells: Occupancy ~36-40 (2 blocks resident; ~18 = VGPR overflow).
//  Win -> conv ~55-75us. Null@occ36 -> per-CU wall; next: split-kernel probe.

typedef int      v4i __attribute__((ext_vector_type(4)));
typedef float    v4f __attribute__((ext_vector_type(4)));

constexpr int B = 64, C = 128, H = 56, W = 56;
constexpr int HP = H + 2, WP = W + 2;      // zero-padded spatial
constexpr int PIX = H * W;                 // 3136
constexpr int M = B * H * W;               // 200704 = 784 * 256
constexpr int NTILES = M / 256;            // 784 tiles of 256 rows
constexpr int TPX = NTILES / 8;            // 98 tiles per XCD

// workspace layout (bytes)
constexpr size_t XS_BYTES = (size_t)B * HP * WP * C;   // 27,557,888
constexpr size_t XS1_OFF = 0;
constexpr size_t XS2_OFF = XS_BYTES;
constexpr size_t WF_BYTES = 18 * 8192;                 // 147,456
constexpr size_t WF1_OFF = 2 * XS_BYTES;
constexpr size_t WF2_OFF = WF1_OFF + WF_BYTES;
constexpr size_t BNP_OFF = WF2_OFF + WF_BYTES;         // 4*128 floats

// ---------------------------------------------------------------------------
// Zero only the padded halos of xs1/xs2. 256 blocks: 4 per image.
__global__ __launch_bounds__(256) void zero_halo(int8_t* __restrict__ xs1,
                                                 int8_t* __restrict__ xs2) {
    int b = blockIdx.x >> 2;
    int q = blockIdx.x & 3;
    int t = q * 256 + threadIdx.x;           // 0..1023
    size_t ib = (size_t)b * HP * WP * C;
#pragma unroll
    for (int a = 0; a < 2; ++a) {
        uint32_t* p = (uint32_t*)((a ? xs2 : xs1) + ib);
        const int ROWD = WP * C / 4;             // 1856 dwords per padded row
        for (int i = t; i < ROWD; i += 1024) {
            p[i] = 0;
            p[(HP - 1) * ROWD + i] = 0;
        }
        for (int i = t; i < 56 * 2 * 32; i += 1024) {
            int r = i >> 6;
            int side = (i >> 5) & 1;
            int j = i & 31;
            p[((r + 1) * WP + side * (WP - 1)) * (C / 4) + j] = 0;
        }
    }
}

// ---------------------------------------------------------------------------
// sign(x) -> padded NHWC int8 via LDS transpose (16 B/lane full-line stores).
__global__ __launch_bounds__(256) void prep_x(const float* __restrict__ x,
                                              int8_t* __restrict__ xs) {
    __shared__ uint32_t tl[256 * 33];
    int t = threadIdx.x;
    int m = blockIdx.x * 256 + t;
    int b_ = m / PIX, hw = m % PIX;
    const float* xp = x + (size_t)b_ * C * PIX + hw;
#pragma unroll
    for (int c4 = 0; c4 < 32; ++c4) {
        uint32_t v = 0;
#pragma unroll
        for (int j = 0; j < 4; ++j) {
            float f = __builtin_nontemporal_load(xp + (size_t)(c4 * 4 + j) * PIX);
            v |= ((uint32_t)(uint8_t)(int8_t)((f > 0.f) - (f < 0.f))) << (8 * j);
        }
        tl[t * 33 + c4] = v;
    }
    __syncthreads();
    int pl = t >> 3, co = t & 7;
#pragma unroll
    for (int pass = 0; pass < 8; ++pass) {
        int p = pass * 32 + pl;
        int mg = blockIdx.x * 256 + p;
        int b2 = mg / PIX, hw2 = mg % PIX, h2 = hw2 / W, w2 = hw2 % W;
        size_t ob = ((size_t)(b2 * HP + h2 + 1) * WP + (w2 + 1)) * C + co * 16;
        v4i val;
#pragma unroll
        for (int k = 0; k < 4; ++k) val[k] = (int)tl[p * 33 + co * 4 + k];
        *(v4i*)(xs + ob) = val;
    }
}

// ---------------------------------------------------------------------------
// Binarize weights into per-O-half MFMA B-fragment order:
// byte index (((slot*2 + ohalf)*4 + nsub)*64 + lane)*16,
// o = ohalf*64 + (lane&15)*4 + nsub, slot = r*6 + kh*3 + s.
// BN tables exactly numpy fp32.
__global__ __launch_bounds__(256) void prep_w(
    const float* __restrict__ w1, const float* __restrict__ w2,
    const float* __restrict__ g1, const float* __restrict__ be1,
    const float* __restrict__ mu1, const float* __restrict__ va1,
    const float* __restrict__ g2, const float* __restrict__ be2,
    const float* __restrict__ mu2, const float* __restrict__ va2,
    int8_t* __restrict__ wf1, int8_t* __restrict__ wf2,
    float* __restrict__ bnp) {
    int t = blockIdx.x * 256 + threadIdx.x;
    if (t < 256) {
        int o = t & 127;
        if (t < 128) {
            float inv = g1[o] / sqrtf(va1[o] + 1e-5f);
            bnp[o]       = inv;
            bnp[128 + o] = __fsub_rn(be1[o], __fmul_rn(mu1[o], inv));
        } else {
            float inv = g2[o] / sqrtf(va2[o] + 1e-5f);
            bnp[256 + o] = inv;
            bnp[384 + o] = __fsub_rn(be2[o], __fmul_rn(mu2[o], inv));
        }
    }
    if (t >= 2 * 18432) return;
    int lane  = t & 63;
    int nsub  = (t >> 6) & 3;
    int ohalf = (t >> 8) & 1;
    int kh    = (t >> 9) & 1;
    int tap   = (t >> 10) % 9;
    int which = (t >> 10) / 9;
    const float* w = which ? w2 : w1;
    int8_t* wf = which ? wf2 : wf1;
    int o = ohalf * 64 + (lane & 15) * 4 + nsub;
    int cbase = kh * 64 + (lane >> 4) * 16;
    int r = tap / 3, s = tap % 3;
    int slot = r * 6 + kh * 3 + s;           // (r, kh, s) step order
    int8_t frag[16];
#pragma unroll
    for (int j = 0; j < 16; ++j) {
        float f = w[((size_t)(o * C + cbase + j) * 3 + r) * 3 + s];
        frag[j] = (int8_t)((f > 0.f) - (f < 0.f));
    }
    *(v4i*)(wf + (size_t)((((slot * 2 + ohalf) * 4 + nsub) * 64 + lane)) * 16) =
        *(const v4i*)frag;
}

// ---------------------------------------------------------------------------
// Counted wait helpers (literal immediates; if constexpr dispatch).
template <int N>
__device__ __forceinline__ void wait_vm() {
    if constexpr (N == 0) asm volatile("s_waitcnt vmcnt(0)");
    else if constexpr (N == 2) asm volatile("s_waitcnt vmcnt(2)");
    else if constexpr (N == 4) asm volatile("s_waitcnt vmcnt(4)");
}
template <int N>
__device__ __forceinline__ void wait_lgkm() {
    if constexpr (N == 0) asm volatile("s_waitcnt lgkmcnt(0)");
    else if constexpr (N == 4) asm volatile("s_waitcnt lgkmcnt(4)");
}

// ---------------------------------------------------------------------------
// K-loop: RG 16-row groups x this block's 64 O. All waits hand-counted:
//  A-side: asm global_load_dwordx4, 3-slot depth-2, vmcnt(2*RG) steady.
//  B-side: asm ds_read_b128, ping-pong depth-1, lgkmcnt(4) steady,
//          drains (vm 0 / lgkm 0) only on the final steps.
template <int RG>
__device__ __forceinline__ void do_conv(
    const int (&mrows)[RG], const int8_t* __restrict__ xs, const int8_t* wlds,
    int lane, int quad, int l15, v4i (&acc)[RG][4])
{
    const int8_t* ap[RG];
#pragma unroll
    for (int rg = 0; rg < RG; ++rg) {
        int ma = mrows[rg] + l15;
        int wa = ma % W; int ta = ma / W; int ha = ta % H; int ba = ta / H;
        ap[rg] = xs + ((ba * HP + ha) * WP + wa) * C + quad * 16;
    }
    // 32-bit LDS byte address (low word of the generic pointer) + lane*16.
    uint32_t bb = (uint32_t)(uintptr_t)wlds + (uint32_t)(lane << 4);

#pragma unroll
    for (int rg = 0; rg < RG; ++rg)
#pragma unroll
        for (int n = 0; n < 4; ++n) acc[rg][n] = (v4i)0;

    v4i a[3][RG];        // A slots; slot(st) = kk%3 (compile-time)
    v4i bf0[4], bf1[4];  // B ping-pong; set = kk&1

    // prologue: A(0)->slot0 (off 0), A(1)->slot1 (off C); B(0)->set0.
#pragma unroll
    for (int rg = 0; rg < RG; ++rg)
        asm volatile("global_load_dwordx4 %0, %1, off"
                     : "=v"(a[0][rg]) : "v"(ap[rg]));
#pragma unroll
    for (int rg = 0; rg < RG; ++rg)
        asm volatile("global_load_dwordx4 %0, %1, off"
                     : "=v"(a[1][rg]) : "v"(ap[rg] + C));
#pragma unroll
    for (int n = 0; n < 4; ++n)
        asm volatile("ds_read_b128 %0, %1"
                     : "=v"(bf0[n]) : "v"(bb + n * 1024));
    __builtin_amdgcn_sched_barrier(0);

    int aoffr = 0;                           // r * WP * C
#pragma unroll 1
    for (int r3 = 0; r3 < 3; ++r3) {
#pragma unroll
        for (int kk = 0; kk < 6; ++kk) {
            // ---- A prefetch: step st+2 -> slot (kk+2)%3 (skip if st+2>17)
            if (kk <= 3 || r3 != 2) {
                const int kp = (kk + 2) % 6;           // target substep
                const int rb = (kk <= 3) ? 0 : WP * C; // crosses r-boundary
                const int noff = rb + (kp / 3) * 64 + (kp % 3) * C;
#pragma unroll
                for (int rg = 0; rg < RG; ++rg) {
                    const int8_t* p = ap[rg] + aoffr + noff;
                    asm volatile("global_load_dwordx4 %0, %1, off"
                                 : "=v"(a[(kk + 2) % 3][rg]) : "v"(p));
                }
            }
            // ---- B prefetch: step st+1 -> set (kk+1)&1 (skip if st+1>17)
            // offset (kk+1)*4096 also handles kk==5 -> next r's slot 0
            // (6*4096 = one r3 stride).
            if (kk < 5 || r3 != 2) {
                if (((kk + 1) & 1) == 0) {
#pragma unroll
                    for (int n = 0; n < 4; ++n)
                        asm volatile("ds_read_b128 %0, %1"
                                     : "=v"(bf0[n])
                                     : "v"(bb + (kk + 1) * 4096 + n * 1024));
                } else {
#pragma unroll
                    for (int n = 0; n < 4; ++n)
                        asm volatile("ds_read_b128 %0, %1"
                                     : "=v"(bf1[n])
                                     : "v"(bb + (kk + 1) * 4096 + n * 1024));
                }
            }
            __builtin_amdgcn_sched_barrier(0);
            // ---- counted waits (never drain mid-loop)
            if (r3 == 2 && kk >= 4) wait_vm<0>();
            else                    wait_vm<2 * RG>();
            __builtin_amdgcn_sched_barrier(0);
            if (r3 == 2 && kk == 5) wait_lgkm<0>();
            else                    wait_lgkm<4>();
            __builtin_amdgcn_sched_barrier(0);
            __builtin_amdgcn_s_setprio(1);
            if ((kk & 1) == 0) {
#pragma unroll
                for (int n = 0; n < 4; ++n)
#pragma unroll
                    for (int rg = 0; rg < RG; ++rg)
                        acc[rg][n] = __builtin_amdgcn_mfma_i32_16x16x64_i8(
                            a[kk % 3][rg], bf0[n], acc[rg][n], 0, 0, 0);
            } else {
#pragma unroll
                for (int n = 0; n < 4; ++n)
#pragma unroll
                    for (int rg = 0; rg < RG; ++rg)
                        acc[rg][n] = __builtin_amdgcn_mfma_i32_16x16x64_i8(
                            a[kk % 3][rg], bf1[n], acc[rg][n], 0, 0, 0);
            }
            __builtin_amdgcn_s_setprio(0);
            __builtin_amdgcn_sched_barrier(0);
        }
        aoffr += WP * C;
        bb += 6 * 4096;                      // next r3's LDS base
    }
}

// ---------------------------------------------------------------------------
// Phase-1 epilogue: sign(bn(acc)) -> xs_next. Per (rg,i): 16 lanes x u32 at
// o-offset ohalf*64 + l15*4 -> 64-B-aligned contiguous sector stores.
template <int RG>
__device__ __forceinline__ void epi_p1(
    v4i (&acc)[RG][4], const int (&mrows)[RG], int quad, int l15, int coff,
    const float* binv, const float* btt, int8_t* __restrict__ xs_next)
{
#pragma unroll
    for (int rg = 0; rg < RG; ++rg) {
        int m0 = mrows[rg] + quad * 4;
        int w0 = m0 % W; int t0 = m0 / W; int h0 = t0 % H; int b0 = t0 / H;
        int base = ((b0 * HP + h0 + 1) * WP + (w0 + 1)) * C + coff + l15 * 4;
#pragma unroll
        for (int i = 0; i < 4; ++i) {
            uint32_t wd = 0;
#pragma unroll
            for (int n = 0; n < 4; ++n) {
                float y = __fadd_rn(__fmul_rn((float)acc[rg][n][i], binv[n]), btt[n]);
                uint32_t sb = (uint8_t)(int8_t)((y > 0.f) - (y < 0.f));
                wd |= sb << (8 * n);
            }
            *(uint32_t*)(xs_next + base + i * C) = wd;
        }
    }
}

// ---------------------------------------------------------------------------
// Phase-2 epilogue (per-wave direct gather): bn + residual + clip.
template <int RG>
__device__ __forceinline__ void epi_p2(
    v4i (&acc)[RG][4], const int (&mrows)[RG], int quad, int l15, int coff,
    const float* binv, const float* btt,
    const float* __restrict__ xres, float* __restrict__ out)
{
#pragma unroll
    for (int rg = 0; rg < RG; ++rg) {
        int m0 = mrows[rg] + quad * 4;                // multiple of 4; W%4==0
        int w0 = m0 % W; int t0 = m0 / W; int h0 = t0 % H; int b0 = t0 / H;
        int pixb = b0 * C * PIX + h0 * W + w0;
#pragma unroll
        for (int n = 0; n < 4; ++n) {
            int idx = pixb + (coff + l15 * 4 + n) * PIX;
            v4f r = __builtin_nontemporal_load((const v4f*)(xres + idx));
            v4f z;
#pragma unroll
            for (int i = 0; i < 4; ++i) {
                float y = __fadd_rn(__fmul_rn((float)acc[rg][n][i], binv[n]), btt[n]);
                float v = __fadd_rn(y, r[i]);
                z[i] = fminf(fmaxf(v, -1.f), 1.f);
            }
            __builtin_nontemporal_store(z, (v4f*)(out + idx));
        }
    }
}

// ---------------------------------------------------------------------------
// Phase 1: persistent conv. 512 blocks (2/CU, LDS 73,728 B), 512 thr =
// 8 waves -> 4 waves/SIMD. Block owns O-half ohalf = local&1.
// Per XCD (64 blocks): 3 rounds x 32 tiles x 2 O-halves, then the 2
// leftover tiles as 8 (half-tile x O-half) tasks on blocks local<8.
template <int PHASE>
__global__ __launch_bounds__(512, 4) void conv_bin(
    const int8_t* __restrict__ xs,
    const int8_t* __restrict__ wf,
    const float* __restrict__ bnp,
    const float* __restrict__ xres,
    int8_t* __restrict__ xs_next,
    float* __restrict__ out)
{
    __shared__ int8_t wlds[18 * 4096];       // 73,728 B -> 2 blocks/CU
    int t = threadIdx.x, lane = t & 63, wv = t >> 6;
    int quad = lane >> 4, l15 = lane & 15;
    int xcd = blockIdx.x & 7, local = blockIdx.x >> 3;   // 64 per XCD
    int ohalf = local & 1, coff = ohalf * 64;

    // one-time weight staging: this block's O-half only.
    // wf v4i idx = slot*512 + ohalf*256 + j  (j = nsub*64+lane in [0,256)).
    {
        const v4i* g = (const v4i*)wf;
        v4i* l = (v4i*)wlds;
        for (int i = t; i < 18 * 256; i += 512)
            l[i] = g[(i >> 8) * 512 + ohalf * 256 + (i & 255)];
    }
    float binv[4], btt[4];
    {
        int o0 = (PHASE == 1 ? 0 : 256) + coff + l15 * 4;
#pragma unroll
        for (int n = 0; n < 4; ++n) { binv[n] = bnp[o0 + n]; btt[n] = bnp[o0 + 128 + n]; }
    }
    __syncthreads();

#pragma unroll 1
    for (int rd = 0; rd < 3; ++rd) {
        int tile = xcd * TPX + (local >> 1) + rd * 32;
        int mw = tile * 256 + wv * 32;
        int mrows2[2] = { mw, mw + 16 };
        v4i acc[2][4];
        do_conv<2>(mrows2, xs, wlds, lane, quad, l15, acc);
        if (PHASE == 1) epi_p1<2>(acc, mrows2, quad, l15, coff, binv, btt, xs_next);
        else            epi_p2<2>(acc, mrows2, quad, l15, coff, binv, btt, xres, out);
    }
    if (local < 8) {                         // 2 leftover tiles per XCD
        int tile = xcd * TPX + 96 + (local >> 2);
        int mh = (local >> 1) & 1;
        int mw = tile * 256 + mh * 128 + wv * 16;
        int mrows1[1] = { mw };
        v4i acc[1][4];
        do_conv<1>(mrows1, xs, wlds, lane, quad, l15, acc);
        if (PHASE == 1) epi_p1<1>(acc, mrows1, quad, l15, coff, binv, btt, xs_next);
        else            epi_p2<1>(acc, mrows1, quad, l15, coff, binv, btt, xres, out);
    }
}

// ---------------------------------------------------------------------------
extern "C" void kernel_launch(void* const* d_in, const int* in_sizes, int n_in,
                              void* d_out, int out_size, void* d_ws, size_t ws_size,
                              hipStream_t stream) {
    const float* x   = (const float*)d_in[0];
    const float* w1  = (const float*)d_in[1];
    const float* w2  = (const float*)d_in[2];
    const float* g1  = (const float*)d_in[3];
    const float* be1 = (const float*)d_in[4];
    const float* mu1 = (const float*)d_in[5];
    const float* va1 = (const float*)d_in[6];
    const float* g2  = (const float*)d_in[7];
    const float* be2 = (const float*)d_in[8];
    const float* mu2 = (const float*)d_in[9];
    const float* va2 = (const float*)d_in[10];

    int8_t* ws  = (int8_t*)d_ws;
    int8_t* xs1 = ws + XS1_OFF;
    int8_t* xs2 = ws + XS2_OFF;
    int8_t* wf1 = ws + WF1_OFF;
    int8_t* wf2 = ws + WF2_OFF;
    float*  bnp = (float*)(ws + BNP_OFF);

    zero_halo<<<256, 256, 0, stream>>>(xs1, xs2);
    prep_x<<<M / 256, 256, 0, stream>>>(x, xs1);
    prep_w<<<(2 * 18432 + 255) / 256, 256, 0, stream>>>(
        w1, w2, g1, be1, mu1, va1, g2, be2, mu2, va2, wf1, wf2, bnp);

    conv_bin<1><<<512, 512, 0, stream>>>(xs1, wf1, bnp, nullptr, xs2, nullptr);
    conv_bin<2><<<512, 512, 0, stream>>>(xs2, wf2, bnp, x, nullptr, (float*)d_out);
}